// Round 14
// baseline (72.256 us; speedup 1.0000x reference)
//
#include <hip/hip_runtime.h>
#include <math.h>

#define NBN 64      // B*N_HEADS
#define DD  64      // head dim
#define SS  1024    // sequence length (H*W)

typedef int i32x4_ __attribute__((ext_vector_type(4)));

// raw v_exp_f32 (no OCML denormal wrapper). Args always well in range here.
#if defined(__has_builtin)
#  if __has_builtin(__builtin_amdgcn_exp2f)
#    define FEXP2(x) __builtin_amdgcn_exp2f(x)
#  endif
#endif
#ifndef FEXP2
#  define FEXP2(x) exp2f(x)
#endif

#if defined(__has_builtin)
#  if __has_builtin(__builtin_amdgcn_cvt_pk_u8_f32)
#    define PK_U8(f, r, old) __builtin_amdgcn_cvt_pk_u8_f32((f), (r), (old))
#  endif
#endif
#ifndef PK_U8
#  define PK_U8(f, r, old) (((old) & ~(0xff << (8*(r)))) | (((int)(f) & 0xff) << (8*(r))))
#endif

__device__ __forceinline__ i32x4_ mfma_i8(i32x4_ a, i32x4_ b, i32x4_ c) {
    // A/B lane: m/n = lane&15, k = (lane>>4)*16 + reg*4 + byte; C/D: col=lane&15, row=(lane>>4)*4+reg
    return __builtin_amdgcn_mfma_i32_16x16x64_i8(a, b, c, 0, 0, 0);
}

// reciprocal-mul quantize: rintf(x*rsc) vs ref's rintf(x/sc) differs <=1ulp of the
// quotient -> rint flips only at half-integer ties (prob ~1e-5/el); +-1 LSB int8
// flips perturb the final output well under threshold. Saves the ~10-op IEEE div chain.
__device__ __forceinline__ int quant_rsc(float x, float rsc) {
    float r = fminf(fmaxf(rintf(x * rsc), -127.0f), 127.0f);
    return (int)r;
}

__device__ __forceinline__ float wave_max256(const float* part, int lane) {
    float4 t = ((const float4*)part)[lane];
    float m = fmaxf(fmaxf(t.x, t.y), fmaxf(t.z, t.w));
    #pragma unroll
    for (int mk = 1; mk <= 32; mk <<= 1) m = fmaxf(m, __shfl_xor(m, mk, 64));
    return m;
}

__device__ __forceinline__ float wave_min4096(const float* part, int lane) {
    float m = 3.4e38f;
    #pragma unroll
    for (int i = 0; i < 16; ++i) {
        float4 u = ((const float4*)part)[lane + i * 64];
        m = fminf(m, fminf(fminf(u.x, u.y), fminf(u.z, u.w)));
    }
    #pragma unroll
    for (int mk = 1; mk <= 32; mk <<= 1) m = fminf(m, __shfl_xor(m, mk, 64));
    return m;
}

// absmax partials: no atomics, no init needed (every slot written every run).
__global__ void k_absmax(const float* __restrict__ q, const float* __restrict__ k,
                         const float* __restrict__ v, float* __restrict__ amax_part) {
    const float* src = (blockIdx.y == 0) ? q : (blockIdx.y == 1) ? k : v;
    const int n = NBN * DD * SS;
    float m = 0.0f;
    for (int i = (blockIdx.x * 256 + threadIdx.x) * 4; i < n; i += gridDim.x * 256 * 4) {
        float4 x = *(const float4*)(src + i);
        m = fmaxf(m, fmaxf(fmaxf(fabsf(x.x), fabsf(x.y)), fmaxf(fabsf(x.z), fabsf(x.w))));
    }
    __shared__ float red[256];
    red[threadIdx.x] = m;
    __syncthreads();
    for (int off = 128; off > 0; off >>= 1) {
        if (threadIdx.x < off) red[threadIdx.x] = fmaxf(red[threadIdx.x], red[threadIdx.x + off]);
        __syncthreads();
    }
    if (threadIdx.x == 0) amax_part[blockIdx.y * 256 + blockIdx.x] = red[0];
}

// Q/K quantize + transpose-pack via LDS tile. grid (16, 64, 2), 256 threads.
// XCD-aligned writer remap (r13); reciprocal-mul quantize (no IEEE div chain).
__global__ void k_quant_qk(const float* __restrict__ q, const float* __restrict__ k,
                           const float* __restrict__ amax_part,
                           int* __restrict__ Qp, int* __restrict__ Kp) {
    __shared__ float TlA[64][69];
    const int which = blockIdx.z;
    const int j = blockIdx.x + (blockIdx.y << 4);          // 0..1023; XCD = j%8
    const int bn = ((j & 7) << 3) | ((j >> 3) & 7);        // j%8 == bn>>3
    const int chunk = j >> 6;
    const int tid = threadIdx.x;
    const float sc = fmaxf(wave_max256(amax_part + which * 256, tid & 63) / 127.0f, 1e-8f);
    const float rsc = 1.0f / sc;
    const float* tsrc = (which ? k : q) + (size_t)bn * DD * SS;
    int* dst = which ? Kp : Qp;
    const int s_base = chunk * 64;
    #pragma unroll
    for (int kk = 0; kk < 4; ++kk) {
        int idx = tid + kk * 256;
        int d = idx >> 4, s4 = idx & 15;
        float4 x = *(const float4*)(tsrc + (size_t)d * SS + s_base + s4 * 4);
        TlA[d][s4*4+0] = x.x; TlA[d][s4*4+1] = x.y;
        TlA[d][s4*4+2] = x.z; TlA[d][s4*4+3] = x.w;
    }
    __syncthreads();
    const int u = tid & 3, s_loc = tid >> 2;
    int pw[4];
    #pragma unroll
    for (int jj = 0; jj < 4; ++jj) {
        int p = 0;
        #pragma unroll
        for (int r = 0; r < 4; ++r) {
            int iq = quant_rsc(TlA[16*u + 4*jj + r][s_loc], rsc);
            p |= (iq & 0xff) << (8 * r);
        }
        pw[jj] = p;
    }
    *(int4*)(dst + ((size_t)bn * SS + s_base + s_loc) * 16 + u * 4)
        = make_int4(pw[0], pw[1], pw[2], pw[3]);
}

// Phase A: grid (64, 64); 8 waves/block; wave = 16 s-rows x 128 t's (dq[8] only ->
// ~64 VGPR, 8 waves/SIMD). Per-row arithmetic identical to the 2-tile version
// (same t-strips, same combine tree). Blocks with y<16 also quantize one V tile.
__global__ __launch_bounds__(512) void k_phase_a(const int* __restrict__ Qp,
    const int* __restrict__ Kp, const float* __restrict__ v,
    const float* __restrict__ amax_part,
    float* __restrict__ m2_arr, float* __restrict__ l_arr, float* __restrict__ minl_part,
    int* __restrict__ Vq)
{
    __shared__ float Mf[8][16];
    __shared__ float Lf[8][16];
    __shared__ __align__(16) int TlB[64][20];
    const int x = blockIdx.x;
    const int bn = ((x & 7) << 3) | ((x >> 3) & 7);   // XCD swizzle
    const int s0 = blockIdx.y * 16;
    const int tid = threadIdx.x;
    const int wv = tid >> 6, lane = tid & 63;
    const int g = lane >> 4, c = lane & 15;

    // ---- fused V-quant (1024 of the 4096 blocks cover 64 bn x 16 tiles) ----
    if (blockIdx.y < 16) {
        const int tb = blockIdx.y;
        const float scv = fmaxf(wave_max256(amax_part + 512, lane) / 127.0f, 1e-8f);
        const float rscv = 1.0f / scv;
        const int d = tid >> 3, t8 = tid & 7;
        #pragma unroll
        for (int i = 0; i < 2; ++i) {
            float4 xx = *(const float4*)(v + (size_t)(bn * 64 + d) * SS + tb * 64 + t8 * 8 + i * 4);
            TlB[d][t8 * 2 + i] = (quant_rsc(xx.x, rscv) & 0xff)
                              | ((quant_rsc(xx.y, rscv) & 0xff) << 8)
                              | ((quant_rsc(xx.z, rscv) & 0xff) << 16)
                              | ((quant_rsc(xx.w, rscv) & 0xff) << 24);
        }
        __syncthreads();
        if (tid < 256) {
            const int dt = tid >> 6, gg = (tid >> 4) & 3;
            const int dd = dt * 16 + (tid & 15);
            int4 w = make_int4(TlB[dd][gg*4+0], TlB[dd][gg*4+1], TlB[dd][gg*4+2], TlB[dd][gg*4+3]);
            *(int4*)(Vq + (size_t)(bn * 16 + tb) * 1024 + tid * 4) = w;
        }
    }

    // ---- main phase A ----
    const float sq = fmaxf(wave_max256(amax_part, lane) / 127.0f, 1e-8f);
    const float sk = fmaxf(wave_max256(amax_part + 256, lane) / 127.0f, 1e-8f);
    const float cqk2 = (sq * sk * 0.125f) * 1.4426950408889634f;  // log2-domain
    const i32x4_ qf = *(const i32x4_*)(Qp + ((size_t)bn * SS + s0 + c) * 16 + g * 4);
    const i32x4_ zero = {0, 0, 0, 0};
    const int* kb = Kp + ((size_t)bn * SS + wv * 128 + c) * 16 + g * 4;

    i32x4_ kfr[8];
    #pragma unroll
    for (int j = 0; j < 8; ++j) kfr[j] = *(const i32x4_*)(kb + j * 256);
    __builtin_amdgcn_sched_barrier(0);                 // all 8 loads in flight before compute
    i32x4_ dq[8];
    #pragma unroll
    for (int j = 0; j < 8; ++j)
        dq[j] = mfma_i8(kfr[j], qf, zero);             // s = s0+c, t = wv*128+16j+4g+r

    int im = -2147483647;
    #pragma unroll
    for (int j = 0; j < 8; ++j)
        im = max(im, max(max(dq[j][0], dq[j][1]), max(dq[j][2], dq[j][3])));
    im = max(im, __shfl_xor(im, 16, 64));
    im = max(im, __shfl_xor(im, 32, 64));
    const float m0 = (float)im * cqk2;                 // wave-local max (monotone map)
    float la = 0.f, lb = 0.f, lc = 0.f, ld = 0.f;
    #pragma unroll
    for (int j = 0; j < 8; ++j) {
        la += FEXP2(fmaf((float)dq[j][0], cqk2, -m0));
        lb += FEXP2(fmaf((float)dq[j][1], cqk2, -m0));
        lc += FEXP2(fmaf((float)dq[j][2], cqk2, -m0));
        ld += FEXP2(fmaf((float)dq[j][3], cqk2, -m0));
    }
    float l0 = (la + lb) + (lc + ld);
    l0 += __shfl_xor(l0, 16, 64);
    l0 += __shfl_xor(l0, 32, 64);
    if (g == 0) { Mf[wv][c] = m0; Lf[wv][c] = l0; }
    __syncthreads();                                   // the ONLY barrier
    if (tid < 16) {
        const int cc = tid;
        float m = Mf[0][cc];
        #pragma unroll
        for (int w = 1; w < 8; ++w) m = fmaxf(m, Mf[w][cc]);
        float l = 0.0f;
        #pragma unroll
        for (int w = 0; w < 8; ++w) l += Lf[w][cc] * FEXP2(Mf[w][cc] - m);
        m2_arr[bn * SS + s0 + cc] = m;
        l_arr[bn * SS + s0 + cc] = l;
        float lm = l;
        #pragma unroll
        for (int mk = 1; mk <= 8; mk <<= 1) lm = fminf(lm, __shfl_xor(lm, mk, 64));
        if (cc == 0) minl_part[blockIdx.y * 64 + blockIdx.x] = lm;   // 4096 partials
    }
}

// Phase B (r9-proven): 8 waves = 4 s-groups x 2 t-halves; K/V double-buffered in LDS;
// quant: exp2 -> rintf -> PK_U8; per-word k2 = (w>>1)&0x7f7f7f7f; epilogue reuses PlS.
__global__ __launch_bounds__(512) void k_phase_b(const int* __restrict__ Qp,
    const int* __restrict__ Kp, const int* __restrict__ Vq,
    const float* __restrict__ amax_part, const float* __restrict__ minl_part,
    const float* __restrict__ m2_arr, const float* __restrict__ l_arr,
    float* __restrict__ out)
{
    __shared__ __align__(16) int Kst[2][2][1024];   // 16 KB
    __shared__ __align__(16) int Vst[2][2][1024];   // 16 KB
    __shared__ __align__(16) int PlS[2816];         // Pl (8x320) / epilogue sbuf (32x67)
    const int f = blockIdx.x + (blockIdx.y << 4);
    const int bn = ((f & 7) << 3) | ((f >> 3) & 7);
    const int sblk = (f >> 6) * 64;
    const int tid = threadIdx.x;
    const int wv = tid >> 6, lane = tid & 63;
    const int g = lane >> 4, c = lane & 15;
    const int sgrp = wv & 3, th = wv >> 2;
    const int s0 = sblk + sgrp * 16;
    const float sq = fmaxf(wave_max256(amax_part, lane) / 127.0f, 1e-8f);
    const float sk = fmaxf(wave_max256(amax_part + 256, lane) / 127.0f, 1e-8f);
    const float sv = fmaxf(wave_max256(amax_part + 512, lane) / 127.0f, 1e-8f);
    const float minl = wave_min4096(minl_part, lane);
    const float cqk2 = (sq * sk * 0.125f) * 1.4426950408889634f;
    const float maxP     = 1.0f / minl;
    const float scale_p  = fmaxf(maxP / 255.0f, 1e-8f);
    const float scale_p2 = fmaxf((255.0f * scale_p) / 127.0f, 1e-8f);
    const float cpv = scale_p2 * sv;
    const float m2 = m2_arr[bn * SS + s0 + c];
    const float l  = l_arr [bn * SS + s0 + c];
    const float bexp = log2f((1.0f / scale_p) / l) - m2;   // x = exp2(dq*cqk2 + bexp)
    const i32x4_ qf = *(const i32x4_*)(Qp + ((size_t)bn * SS + s0 + c) * 16 + g * 4);
    const i32x4_ zero = {0, 0, 0, 0};
    int* myP = PlS + wv * 320;
    const int woff = c * 20 + g * 4;
    const int tb0 = th * 8;
    const int soff = sgrp * 256 + lane * 4;
    const int* kg = Kp + (size_t)bn * SS * 16 + soff;   // + tb*1024
    const int* vg = Vq + (size_t)bn * 16384 + soff;     // + tb*1024

    i32x4_ acc[4] = {zero, zero, zero, zero};

    {   // prologue: stage tb0 into buf 0
        i32x4_ gk = *(const i32x4_*)(kg + tb0 * 1024);
        i32x4_ gv = *(const i32x4_*)(vg + tb0 * 1024);
        *(i32x4_*)&Kst[0][th][soff] = gk;
        *(i32x4_*)&Vst[0][th][soff] = gv;
    }
    __syncthreads();

    #pragma unroll
    for (int i = 0; i < 8; ++i) {
        const int b = i & 1;
        i32x4_ gk, gv;
        if (i < 7) {                                   // issue next tile's loads early
            gk = *(const i32x4_*)(kg + (tb0 + i + 1) * 1024);
            gv = *(const i32x4_*)(vg + (tb0 + i + 1) * 1024);
        }
        __builtin_amdgcn_sched_barrier(0);
        int W[4];
        #pragma unroll
        for (int j = 0; j < 4; ++j) {                  // QK + quantize P
            i32x4_ kf = *(const i32x4_*)&Kst[b][th][j * 256 + c * 16 + g * 4];
            i32x4_ dq = mfma_i8(kf, qf, zero);
            int w = 0;
            #pragma unroll
            for (int r = 0; r < 4; ++r) {
                float xx = FEXP2(fmaf((float)dq[r], cqk2, bexp));
                w = PK_U8(rintf(xx), r, w);            // k1 byte insert (pre-rounded)
            }
            W[j] = (w >> 1) & 0x7f7f7f7f;              // per-byte k2 = k1>>1
        }
        i32x4_ wv4 = {W[0], W[1], W[2], W[3]};
        *(i32x4_*)(myP + woff) = wv4;                  // publish W(tb)
        i32x4_ pa;                                     // word-transpose read
        pa[0] = myP[c * 20 + 0 + g];
        pa[1] = myP[c * 20 + 4 + g];
        pa[2] = myP[c * 20 + 8 + g];
        pa[3] = myP[c * 20 + 12 + g];
        #pragma unroll
        for (int dt = 0; dt < 4; ++dt) {
            i32x4_ vf = *(const i32x4_*)&Vst[b][th][dt * 256 + g * 64 + c * 4];
            acc[dt] = mfma_i8(pa, vf, acc[dt]);
        }
        if (i < 7) {                                   // land next tile
            *(i32x4_*)&Kst[b ^ 1][th][soff] = gk;
            *(i32x4_*)&Vst[b ^ 1][th][soff] = gv;
        }
        __syncthreads();
    }

    // epilogue: combine t-halves (exact int add) + scale + coalesced store, reusing PlS.
    int* sbuf = PlS;
    #pragma unroll
    for (int ch = 0; ch < 2; ++ch) {
        if (th == 0) {
            #pragma unroll
            for (int dt = 0; dt < 2; ++dt)
                #pragma unroll
                for (int r = 0; r < 4; ++r)
                    sbuf[(dt * 16 + c) * 67 + sgrp * 16 + 4 * g + r] = acc[ch * 2 + dt][r];
        }
        __syncthreads();
        if (th == 1) {
            #pragma unroll
            for (int dt = 0; dt < 2; ++dt)
                #pragma unroll
                for (int r = 0; r < 4; ++r) {
                    const int slot = (dt * 16 + c) * 67 + sgrp * 16 + 4 * g + r;
                    ((float*)sbuf)[slot] = (float)(sbuf[slot] + acc[ch * 2 + dt][r]) * cpv;
                }
        }
        __syncthreads();
        {
            const int d = tid >> 4, sq4 = tid & 15;
            const float* fb = (const float*)sbuf + d * 67 + sq4 * 4;
            float4 val = make_float4(fb[0], fb[1], fb[2], fb[3]);
            *(float4*)(out + (size_t)bn * 65536 + (size_t)(ch * 32 + d) * 1024 + sblk + sq4 * 4) = val;
        }
        __syncthreads();
    }
}

extern "C" void kernel_launch(void* const* d_in, const int* in_sizes, int n_in,
                              void* d_out, int out_size, void* d_ws, size_t ws_size,
                              hipStream_t stream) {
    const float* q = (const float*)d_in[0];
    const float* k = (const float*)d_in[1];
    const float* v = (const float*)d_in[2];
    float* out = (float*)d_out;
    char* ws = (char*)d_ws;

    float* amax_part = (float*)ws;                                // 3*256 floats
    float* minl_part = (float*)(ws + 4096);                       // 4096 floats (16 KB)
    int* Qp      = (int*)(ws + 32768);                            // 4 MB
    int* Kp      = (int*)(ws + 32768 + (size_t)(1 << 22));        // 4 MB
    int* Vq      = (int*)(ws + 32768 + (size_t)(2 << 22));        // 4 MB
    float* m2    = (float*)(ws + 32768 + (size_t)(3 << 22));      // 256 KB
    float* l_a   = (float*)(ws + 32768 + (size_t)(3 << 22) + (1 << 18)); // 256 KB

    k_absmax<<<dim3(256, 3), 256, 0, stream>>>(q, k, v, amax_part);
    k_quant_qk<<<dim3(16, NBN, 2), 256, 0, stream>>>(q, k, amax_part, Qp, Kp);
    k_phase_a<<<dim3(64, 64), 512, 0, stream>>>(Qp, Kp, v, amax_part, m2, l_a, minl_part, Vq);
    k_phase_b<<<dim3(16, NBN), 512, 0, stream>>>(Qp, Kp, Vq, amax_part, minl_part, m2, l_a, out);
}

// Round 15
// 65.955 us; speedup vs baseline: 1.0955x; 1.0955x over previous
//
#include <hip/hip_runtime.h>
#include <math.h>

#define NBN 64      // B*N_HEADS
#define DD  64      // head dim
#define SS  1024    // sequence length (H*W)

typedef int i32x4_ __attribute__((ext_vector_type(4)));

// raw v_exp_f32 (no OCML denormal wrapper). Args always well in range here.
#if defined(__has_builtin)
#  if __has_builtin(__builtin_amdgcn_exp2f)
#    define FEXP2(x) __builtin_amdgcn_exp2f(x)
#  endif
#endif
#ifndef FEXP2
#  define FEXP2(x) exp2f(x)
#endif

#if defined(__has_builtin)
#  if __has_builtin(__builtin_amdgcn_cvt_pk_u8_f32)
#    define PK_U8(f, r, old) __builtin_amdgcn_cvt_pk_u8_f32((f), (r), (old))
#  endif
#endif
#ifndef PK_U8
#  define PK_U8(f, r, old) (((old) & ~(0xff << (8*(r)))) | (((int)(f) & 0xff) << (8*(r))))
#endif

__device__ __forceinline__ i32x4_ mfma_i8(i32x4_ a, i32x4_ b, i32x4_ c) {
    // A/B lane: m/n = lane&15, k = (lane>>4)*16 + reg*4 + byte; C/D: col=lane&15, row=(lane>>4)*4+reg
    return __builtin_amdgcn_mfma_i32_16x16x64_i8(a, b, c, 0, 0, 0);
}

// reciprocal-mul quantize: rintf(x*rsc) vs rintf(x/sc) differs <=1ulp of the quotient;
// rint flips only at half-integer ties (~1e-5/element), +-1 LSB int8 -> far under threshold.
__device__ __forceinline__ int quant_rsc(float x, float rsc) {
    float r = fminf(fmaxf(rintf(x * rsc), -127.0f), 127.0f);
    return (int)r;
}

__device__ __forceinline__ float wave_max256(const float* part, int lane) {
    float4 t = ((const float4*)part)[lane];
    float m = fmaxf(fmaxf(t.x, t.y), fmaxf(t.z, t.w));
    #pragma unroll
    for (int mk = 1; mk <= 32; mk <<= 1) m = fmaxf(m, __shfl_xor(m, mk, 64));
    return m;
}

__device__ __forceinline__ float wave_min2048(const float* part, int lane) {
    float4 t = ((const float4*)part)[lane];
    float m = fminf(fminf(t.x, t.y), fminf(t.z, t.w));
    #pragma unroll
    for (int i = 1; i < 8; ++i) {
        float4 u = ((const float4*)part)[lane + i * 64];
        m = fminf(m, fminf(fminf(u.x, u.y), fminf(u.z, u.w)));
    }
    #pragma unroll
    for (int mk = 1; mk <= 32; mk <<= 1) m = fminf(m, __shfl_xor(m, mk, 64));
    return m;
}

// absmax partials: no atomics, no init needed (every slot written every run).
__global__ void k_absmax(const float* __restrict__ q, const float* __restrict__ k,
                         const float* __restrict__ v, float* __restrict__ amax_part) {
    const float* src = (blockIdx.y == 0) ? q : (blockIdx.y == 1) ? k : v;
    const int n = NBN * DD * SS;
    float m = 0.0f;
    for (int i = (blockIdx.x * 256 + threadIdx.x) * 4; i < n; i += gridDim.x * 256 * 4) {
        float4 x = *(const float4*)(src + i);
        m = fmaxf(m, fmaxf(fmaxf(fabsf(x.x), fabsf(x.y)), fmaxf(fabsf(x.z), fabsf(x.w))));
    }
    __shared__ float red[256];
    red[threadIdx.x] = m;
    __syncthreads();
    for (int off = 128; off > 0; off >>= 1) {
        if (threadIdx.x < off) red[threadIdx.x] = fmaxf(red[threadIdx.x], red[threadIdx.x + off]);
        __syncthreads();
    }
    if (threadIdx.x == 0) amax_part[blockIdx.y * 256 + blockIdx.x] = red[0];
}

// Fused quantize kernel. grid (16, 64, 3), 256 threads.
// z<2: Q/K quantize + transpose-pack via LDS tile; z=2: V pack into PV B-fragment order.
__global__ void k_quant_qkv(const float* __restrict__ q, const float* __restrict__ k,
                            const float* __restrict__ v, const float* __restrict__ amax_part,
                            int* __restrict__ Qp, int* __restrict__ Kp, int* __restrict__ Vq) {
    __shared__ float TlA[64][69];
    __shared__ __align__(16) int TlB[64][20];
    const int which = blockIdx.z;
    const int bn = blockIdx.y;
    const int tid = threadIdx.x;
    const float sc = fmaxf(wave_max256(amax_part + which * 256, tid & 63) / 127.0f, 1e-8f);
    const float rsc = 1.0f / sc;
    if (which < 2) {
        const float* tsrc = (which ? k : q) + (size_t)bn * DD * SS;
        int* dst = which ? Kp : Qp;
        const int s_base = blockIdx.x * 64;
        #pragma unroll
        for (int kk = 0; kk < 4; ++kk) {
            int idx = tid + kk * 256;
            int d = idx >> 4, s4 = idx & 15;
            float4 x = *(const float4*)(tsrc + (size_t)d * SS + s_base + s4 * 4);
            TlA[d][s4*4+0] = x.x; TlA[d][s4*4+1] = x.y;
            TlA[d][s4*4+2] = x.z; TlA[d][s4*4+3] = x.w;
        }
        __syncthreads();
        const int u = tid & 3, s_loc = tid >> 2;
        int pw[4];
        #pragma unroll
        for (int jj = 0; jj < 4; ++jj) {
            int p = 0;
            #pragma unroll
            for (int r = 0; r < 4; ++r) {
                int iq = quant_rsc(TlA[16*u + 4*jj + r][s_loc], rsc);
                p |= (iq & 0xff) << (8 * r);
            }
            pw[jj] = p;
        }
        *(int4*)(dst + ((size_t)bn * SS + s_base + s_loc) * 16 + u * 4)
            = make_int4(pw[0], pw[1], pw[2], pw[3]);
    } else {
        const int tb = blockIdx.x;
        {
            const int d = tid >> 2, tqq = tid & 3;
            #pragma unroll
            for (int i = 0; i < 4; ++i) {
                const int tq = tqq * 4 + i;
                float4 x = *(const float4*)(v + (size_t)(bn * 64 + d) * SS + tb * 64 + tq * 4);
                TlB[d][tq] = (quant_rsc(x.x, rsc) & 0xff)
                          | ((quant_rsc(x.y, rsc) & 0xff) << 8)
                          | ((quant_rsc(x.z, rsc) & 0xff) << 16)
                          | ((quant_rsc(x.w, rsc) & 0xff) << 24);
            }
        }
        __syncthreads();
        {
            const int dt = tid >> 6, gg = (tid >> 4) & 3;
            const int d = dt * 16 + (tid & 15);
            int4 w = make_int4(TlB[d][gg*4+0], TlB[d][gg*4+1], TlB[d][gg*4+2], TlB[d][gg*4+3]);
            *(int4*)(Vq + (size_t)(bn * 16 + tb) * 1024 + tid * 4) = w;
        }
    }
}

// Phase A: 8 waves/block; wave = 32 s-rows x 128 t's off the SAME 8 K-fragments.
// ONE barrier: wave-local max -> exp2 immediately; epilogue combines via
// l = sum_w l_w * exp2(m_w - m). minl as plain per-block partial store.
__global__ __launch_bounds__(512) void k_phase_a(const int* __restrict__ Qp,
    const int* __restrict__ Kp, const float* __restrict__ amax_part,
    float* __restrict__ m2_arr, float* __restrict__ l_arr, float* __restrict__ minl_part)
{
    __shared__ float Mf[8][32];
    __shared__ float Lf[8][32];
    const int x = blockIdx.x;
    const int bn = ((x & 7) << 3) | ((x >> 3) & 7);   // XCD swizzle
    const int s0 = blockIdx.y * 32;
    const int tid = threadIdx.x;
    const int wv = tid >> 6, lane = tid & 63;
    const int g = lane >> 4, c = lane & 15;
    const float sq = fmaxf(wave_max256(amax_part, lane) / 127.0f, 1e-8f);
    const float sk = fmaxf(wave_max256(amax_part + 256, lane) / 127.0f, 1e-8f);
    const float cqk2 = (sq * sk * 0.125f) * 1.4426950408889634f;  // log2-domain
    const i32x4_ qf0 = *(const i32x4_*)(Qp + ((size_t)bn * SS + s0 + c) * 16 + g * 4);
    const i32x4_ qf1 = *(const i32x4_*)(Qp + ((size_t)bn * SS + s0 + 16 + c) * 16 + g * 4);
    const i32x4_ zero = {0, 0, 0, 0};
    const int* kb = Kp + ((size_t)bn * SS + wv * 128 + c) * 16 + g * 4;

    i32x4_ kfr[8];
    #pragma unroll
    for (int j = 0; j < 8; ++j) kfr[j] = *(const i32x4_*)(kb + j * 256);
    __builtin_amdgcn_sched_barrier(0);                 // all 8 loads in flight before compute
    i32x4_ dq0[8], dq1[8];
    #pragma unroll
    for (int j = 0; j < 8; ++j) {
        dq0[j] = mfma_i8(kfr[j], qf0, zero);           // s = s0+c,    t = wv*128+16j+4g+r
        dq1[j] = mfma_i8(kfr[j], qf1, zero);           // s = s0+16+c
    }

    int im0 = -2147483647, im1 = -2147483647;
    #pragma unroll
    for (int j = 0; j < 8; ++j) {
        im0 = max(im0, max(max(dq0[j][0], dq0[j][1]), max(dq0[j][2], dq0[j][3])));
        im1 = max(im1, max(max(dq1[j][0], dq1[j][1]), max(dq1[j][2], dq1[j][3])));
    }
    im0 = max(im0, __shfl_xor(im0, 16, 64));
    im0 = max(im0, __shfl_xor(im0, 32, 64));
    im1 = max(im1, __shfl_xor(im1, 16, 64));
    im1 = max(im1, __shfl_xor(im1, 32, 64));
    const float m0 = (float)im0 * cqk2;                // wave-local max
    const float m1 = (float)im1 * cqk2;
    float la0 = 0.f, lb0 = 0.f, lc0 = 0.f, ld0 = 0.f;
    float la1 = 0.f, lb1 = 0.f, lc1 = 0.f, ld1 = 0.f;
    #pragma unroll
    for (int j = 0; j < 8; ++j) {
        la0 += FEXP2(fmaf((float)dq0[j][0], cqk2, -m0));
        lb0 += FEXP2(fmaf((float)dq0[j][1], cqk2, -m0));
        lc0 += FEXP2(fmaf((float)dq0[j][2], cqk2, -m0));
        ld0 += FEXP2(fmaf((float)dq0[j][3], cqk2, -m0));
        la1 += FEXP2(fmaf((float)dq1[j][0], cqk2, -m1));
        lb1 += FEXP2(fmaf((float)dq1[j][1], cqk2, -m1));
        lc1 += FEXP2(fmaf((float)dq1[j][2], cqk2, -m1));
        ld1 += FEXP2(fmaf((float)dq1[j][3], cqk2, -m1));
    }
    float l0 = (la0 + lb0) + (lc0 + ld0);
    float l1 = (la1 + lb1) + (lc1 + ld1);
    l0 += __shfl_xor(l0, 16, 64);
    l0 += __shfl_xor(l0, 32, 64);
    l1 += __shfl_xor(l1, 16, 64);
    l1 += __shfl_xor(l1, 32, 64);
    if (g == 0) {
        Mf[wv][c] = m0;      Lf[wv][c] = l0;
        Mf[wv][16 + c] = m1; Lf[wv][16 + c] = l1;
    }
    __syncthreads();                                   // the ONLY barrier
    if (tid < 32) {
        const int cc = tid;
        float m = Mf[0][cc];
        #pragma unroll
        for (int w = 1; w < 8; ++w) m = fmaxf(m, Mf[w][cc]);
        float l = 0.0f;
        #pragma unroll
        for (int w = 0; w < 8; ++w) l += Lf[w][cc] * FEXP2(Mf[w][cc] - m);
        m2_arr[bn * SS + s0 + cc] = m;
        l_arr[bn * SS + s0 + cc] = l;
        float lm = l;
        #pragma unroll
        for (int mk = 1; mk <= 16; mk <<= 1) lm = fminf(lm, __shfl_xor(lm, mk, 64));
        if (cc == 0) minl_part[blockIdx.y * 64 + blockIdx.x] = lm;
    }
}

// Phase B: 8 waves = 4 s-groups x 2 t-halves. K/V tiles double-buffered in LDS;
// loads issued early, one barrier per iteration. Quant: exp2 -> rintf -> PK_U8,
// per-word k2 = (w>>1)&0x7f7f7f7f. Epilogue combine reuses the Pl LDS region.
__global__ __launch_bounds__(512) void k_phase_b(const int* __restrict__ Qp,
    const int* __restrict__ Kp, const int* __restrict__ Vq,
    const float* __restrict__ amax_part, const float* __restrict__ minl_part,
    const float* __restrict__ m2_arr, const float* __restrict__ l_arr,
    float* __restrict__ out)
{
    __shared__ __align__(16) int Kst[2][2][1024];   // [buf][th][tile] 16 KB
    __shared__ __align__(16) int Vst[2][2][1024];   // 16 KB
    __shared__ __align__(16) int PlS[2816];         // Pl (8x320) / epilogue sbuf (32x67)
    const int f = blockIdx.x + (blockIdx.y << 4);
    const int bn = ((f & 7) << 3) | ((f >> 3) & 7);
    const int sblk = (f >> 6) * 64;
    const int tid = threadIdx.x;
    const int wv = tid >> 6, lane = tid & 63;
    const int g = lane >> 4, c = lane & 15;
    const int sgrp = wv & 3, th = wv >> 2;
    const int s0 = sblk + sgrp * 16;
    const float sq = fmaxf(wave_max256(amax_part, lane) / 127.0f, 1e-8f);
    const float sk = fmaxf(wave_max256(amax_part + 256, lane) / 127.0f, 1e-8f);
    const float sv = fmaxf(wave_max256(amax_part + 512, lane) / 127.0f, 1e-8f);
    const float minl = wave_min2048(minl_part, lane);
    const float cqk2 = (sq * sk * 0.125f) * 1.4426950408889634f;
    const float maxP     = 1.0f / minl;
    const float scale_p  = fmaxf(maxP / 255.0f, 1e-8f);
    const float scale_p2 = fmaxf((255.0f * scale_p) / 127.0f, 1e-8f);
    const float cpv = scale_p2 * sv;
    const float m2 = m2_arr[bn * SS + s0 + c];
    const float l  = l_arr [bn * SS + s0 + c];
    const float bexp = log2f((1.0f / scale_p) / l) - m2;   // x = exp2(dq*cqk2 + bexp)
    const i32x4_ qf = *(const i32x4_*)(Qp + ((size_t)bn * SS + s0 + c) * 16 + g * 4);
    const i32x4_ zero = {0, 0, 0, 0};
    int* myP = PlS + wv * 320;
    const int woff = c * 20 + g * 4;
    const int tb0 = th * 8;
    const int soff = sgrp * 256 + lane * 4;
    const int* kg = Kp + (size_t)bn * SS * 16 + soff;   // + tb*1024
    const int* vg = Vq + (size_t)bn * 16384 + soff;     // + tb*1024

    i32x4_ acc[4] = {zero, zero, zero, zero};

    {   // prologue: stage tb0 into buf 0
        i32x4_ gk = *(const i32x4_*)(kg + tb0 * 1024);
        i32x4_ gv = *(const i32x4_*)(vg + tb0 * 1024);
        *(i32x4_*)&Kst[0][th][soff] = gk;
        *(i32x4_*)&Vst[0][th][soff] = gv;
    }
    __syncthreads();

    #pragma unroll
    for (int i = 0; i < 8; ++i) {
        const int b = i & 1;
        i32x4_ gk, gv;
        if (i < 7) {                                   // issue next tile's loads early
            gk = *(const i32x4_*)(kg + (tb0 + i + 1) * 1024);
            gv = *(const i32x4_*)(vg + (tb0 + i + 1) * 1024);
        }
        __builtin_amdgcn_sched_barrier(0);
        int W[4];
        #pragma unroll
        for (int j = 0; j < 4; ++j) {                  // QK + quantize P
            i32x4_ kf = *(const i32x4_*)&Kst[b][th][j * 256 + c * 16 + g * 4];
            i32x4_ dq = mfma_i8(kf, qf, zero);
            int w = 0;
            #pragma unroll
            for (int r = 0; r < 4; ++r) {
                float xx = FEXP2(fmaf((float)dq[r], cqk2, bexp));
                w = PK_U8(rintf(xx), r, w);            // k1 byte insert (pre-rounded)
            }
            W[j] = (w >> 1) & 0x7f7f7f7f;              // per-byte k2 = k1>>1
        }
        i32x4_ wv4 = {W[0], W[1], W[2], W[3]};
        *(i32x4_*)(myP + woff) = wv4;                  // publish W(tb)
        i32x4_ pa;                                     // word-transpose read
        pa[0] = myP[c * 20 + 0 + g];
        pa[1] = myP[c * 20 + 4 + g];
        pa[2] = myP[c * 20 + 8 + g];
        pa[3] = myP[c * 20 + 12 + g];
        #pragma unroll
        for (int dt = 0; dt < 4; ++dt) {
            i32x4_ vf = *(const i32x4_*)&Vst[b][th][dt * 256 + g * 64 + c * 4];
            acc[dt] = mfma_i8(pa, vf, acc[dt]);
        }
        if (i < 7) {                                   // land next tile
            *(i32x4_*)&Kst[b ^ 1][th][soff] = gk;
            *(i32x4_*)&Vst[b ^ 1][th][soff] = gv;
        }
        __syncthreads();
    }

    // epilogue: combine t-halves (exact int add) + scale + coalesced store, reusing PlS.
    int* sbuf = PlS;
    #pragma unroll
    for (int ch = 0; ch < 2; ++ch) {
        if (th == 0) {
            #pragma unroll
            for (int dt = 0; dt < 2; ++dt)
                #pragma unroll
                for (int r = 0; r < 4; ++r)
                    sbuf[(dt * 16 + c) * 67 + sgrp * 16 + 4 * g + r] = acc[ch * 2 + dt][r];
        }
        __syncthreads();
        if (th == 1) {
            #pragma unroll
            for (int dt = 0; dt < 2; ++dt)
                #pragma unroll
                for (int r = 0; r < 4; ++r) {
                    const int slot = (dt * 16 + c) * 67 + sgrp * 16 + 4 * g + r;
                    ((float*)sbuf)[slot] = (float)(sbuf[slot] + acc[ch * 2 + dt][r]) * cpv;
                }
        }
        __syncthreads();
        {
            const int d = tid >> 4, sq4 = tid & 15;
            const float* fb = (const float*)sbuf + d * 67 + sq4 * 4;
            float4 val = make_float4(fb[0], fb[1], fb[2], fb[3]);
            *(float4*)(out + (size_t)bn * 65536 + (size_t)(ch * 32 + d) * 1024 + sblk + sq4 * 4) = val;
        }
        __syncthreads();
    }
}

extern "C" void kernel_launch(void* const* d_in, const int* in_sizes, int n_in,
                              void* d_out, int out_size, void* d_ws, size_t ws_size,
                              hipStream_t stream) {
    const float* q = (const float*)d_in[0];
    const float* k = (const float*)d_in[1];
    const float* v = (const float*)d_in[2];
    float* out = (float*)d_out;
    char* ws = (char*)d_ws;

    float* amax_part = (float*)ws;                                // 3*256 floats
    float* minl_part = (float*)(ws + 4096);                       // 2048 floats
    int* Qp      = (int*)(ws + 16384);                            // 4 MB
    int* Kp      = (int*)(ws + 16384 + (size_t)(1 << 22));        // 4 MB
    int* Vq      = (int*)(ws + 16384 + (size_t)(2 << 22));        // 4 MB
    float* m2    = (float*)(ws + 16384 + (size_t)(3 << 22));      // 256 KB
    float* l_a   = (float*)(ws + 16384 + (size_t)(3 << 22) + (1 << 18)); // 256 KB

    k_absmax<<<dim3(256, 3), 256, 0, stream>>>(q, k, v, amax_part);
    k_quant_qkv<<<dim3(16, NBN, 3), 256, 0, stream>>>(q, k, v, amax_part, Qp, Kp, Vq);
    k_phase_a<<<dim3(64, 32), 512, 0, stream>>>(Qp, Kp, amax_part, m2, l_a, minl_part);
    k_phase_b<<<dim3(16, NBN), 512, 0, stream>>>(Qp, Kp, Vq, amax_part, minl_part, m2, l_a, out);
}